// Round 2
// baseline (304.486 us; speedup 1.0000x reference)
//
#include <hip/hip_runtime.h>
#include <hip/hip_bf16.h>

#define FIN 4096
#define FOUT 4096
#define HEADS 4
#define ROWS_PER_HEAD (FOUT / HEADS)  // 1024
#define M_DIM 4096                    // 2*2048 flattened batch*seq

typedef __attribute__((ext_vector_type(8))) short bf16x8;   // 8 bf16 = 4 VGPRs
typedef __attribute__((ext_vector_type(4))) float floatx4;  // MFMA accum

#define CAST_BLOCKS ((M_DIM * FIN) / (256 * 8))      // 8192
#define TRANS_BLOCKS ((FOUT * FIN / 8) / 256)        // 8192

// ---------------------------------------------------------------------------
// Kernel 1 (merged prep, unchanged from R5-verified).
// ---------------------------------------------------------------------------
__global__ __launch_bounds__(256) void prep(
    const float* __restrict__ x,    // activations [M_DIM][FIN]
    __hip_bfloat16* __restrict__ y, // bf16 activations out
    const float* __restrict__ W,
    const float* __restrict__ cw,   // [HEADS][3][3]
    const float* __restrict__ cb,   // [HEADS]
    const float* __restrict__ sk,   // [HEADS]
    __hip_bfloat16* __restrict__ Wt) {
  if (blockIdx.x < CAST_BLOCKS) {
    int idx = blockIdx.x * 256 + threadIdx.x;  // one per 8 elements
    const float4* xv = (const float4*)x;
    float4 a = xv[idx * 2];
    float4 b = xv[idx * 2 + 1];
    __hip_bfloat16 t[8];
    t[0] = __float2bfloat16(a.x); t[1] = __float2bfloat16(a.y);
    t[2] = __float2bfloat16(a.z); t[3] = __float2bfloat16(a.w);
    t[4] = __float2bfloat16(b.x); t[5] = __float2bfloat16(b.y);
    t[6] = __float2bfloat16(b.z); t[7] = __float2bfloat16(b.w);
    *(bf16x8*)(&y[(size_t)idx * 8]) = *(bf16x8*)t;
    return;
  }

  int gid = (blockIdx.x - CAST_BLOCKS) * 256 + threadIdx.x;
  int o = gid >> 9;                          // output row (FIN/8 = 512)
  int fs = (gid & 511) << 3;                 // fin start, multiple of 8
  int h = o >> 10;                           // head
  int r = o & (ROWS_PER_HEAD - 1);

  float kk[3][3];
#pragma unroll
  for (int i = 0; i < 3; i++)
#pragma unroll
    for (int j = 0; j < 3; j++) kk[i][j] = cw[h * 9 + i * 3 + j];
  float sig = 1.0f / (1.0f + __expf(-sk[h]));

  float acc[8];
#pragma unroll
  for (int j = 0; j < 8; j++) acc[j] = cb[h];

#pragma unroll
  for (int dr = -1; dr <= 1; dr++) {
    int rr = r + dr;
    if (rr < 0 || rr >= ROWS_PER_HEAD) continue;
    const float* rp = W + ((size_t)(h * ROWS_PER_HEAD + rr)) * FIN + fs;
    float a[10];
    float4 v0 = *(const float4*)rp;
    float4 v1 = *(const float4*)(rp + 4);
    a[1] = v0.x; a[2] = v0.y; a[3] = v0.z; a[4] = v0.w;
    a[5] = v1.x; a[6] = v1.y; a[7] = v1.z; a[8] = v1.w;
    a[0] = (fs > 0) ? rp[-1] : 0.0f;
    a[9] = (fs + 8 < FIN) ? rp[8] : 0.0f;
#pragma unroll
    for (int j = 0; j < 8; j++)
      acc[j] += kk[dr + 1][0] * a[j] + kk[dr + 1][1] * a[j + 1] +
                kk[dr + 1][2] * a[j + 2];
    if (dr == 0) {
#pragma unroll
      for (int j = 0; j < 8; j++) acc[j] += sig * a[j + 1];
    }
  }
  __hip_bfloat16 t[8];
#pragma unroll
  for (int j = 0; j < 8; j++) t[j] = __float2bfloat16(acc[j]);
  *(bf16x8*)(&Wt[(size_t)o * FIN + fs]) = *(bf16x8*)t;
}

// ---------------------------------------------------------------------------
// Kernel 2: C[m][n] = sum_k A[m][k] * B[n][k]  (NT GEMM, bf16 in, FP32 out)
// R9: same 8-phase/counted-vmcnt schedule as R8, but with EIGHT DISTINCT
// __shared__ arrays (one per buf x half x operand). R8's single As[2][2]/
// Bs[2][2] arrays made every ds_read may-alias outstanding global_load_lds
// DMA writes -> backend inserted per-phase vmcnt drains that collapsed the
// prefetch pipeline (MfmaUtil 40%). Distinct objects give the waitcnt pass
// precise aliasing: each array's last DMA is >=4 phases old and already
// covered by the explicit WAITVM(4). Compile-time buf via explicit 2-tile
// loop body. Phase sync pinned per m201: sched_barrier; s_barrier;
// lgkmcnt(0); sched_barrier; MFMA(setprio); s_barrier. Plus XCD-chunked
// block swizzle (256 wgs % 8 == 0 -> simple bijective form).
// ---------------------------------------------------------------------------
__device__ static inline void gload_lds16(const void* g, void* l) {
  __builtin_amdgcn_global_load_lds(
      (const __attribute__((address_space(1))) void*)g,
      (__attribute__((address_space(3))) void*)l, 16, 0, 0);
}

#define BK 64
#define NT (FIN / BK)  // 64 K-tiles

__global__ __launch_bounds__(512, 2) void gemm_nt(
    const __hip_bfloat16* __restrict__ A,  // [M][K]
    const __hip_bfloat16* __restrict__ B,  // [N][K]  (= W_i, row-major)
    float* __restrict__ C,                 // [M][N] fp32
    int M, int N, int K) {
  // 8 distinct LDS objects: [128 rows][64 bf16] = 16 KB each, 128 KB total.
  __shared__ __hip_bfloat16 As0h0[128 * BK];
  __shared__ __hip_bfloat16 As0h1[128 * BK];
  __shared__ __hip_bfloat16 As1h0[128 * BK];
  __shared__ __hip_bfloat16 As1h1[128 * BK];
  __shared__ __hip_bfloat16 Bs0h0[128 * BK];
  __shared__ __hip_bfloat16 Bs0h1[128 * BK];
  __shared__ __hip_bfloat16 Bs1h0[128 * BK];
  __shared__ __hip_bfloat16 Bs1h1[128 * BK];

  const int tid = threadIdx.x;
  const int lane = tid & 63;
  const int wave = tid >> 6;   // 0..7
  const int wr = wave >> 2;    // 0..1  (WARPS_M = 2)
  const int wn = wave & 3;     // 0..3  (WARPS_N = 4)
  const int fr = lane & 15;    // fragment row
  const int quad = lane >> 4;  // k-chunk selector
  const int sel = fr & 7;      // swizzle selector

  // XCD-chunked bijective swizzle: 256 wgs, 8 XCDs -> 32 consecutive tiles
  // per XCD (2 full grid rows: 2 A-panels = 4 MB, L2-resident per XCD).
  const int orig = blockIdx.y * gridDim.x + blockIdx.x;
  const int swz = (orig & 7) * 32 + (orig >> 3);
  const int tile_m = (swz >> 4) * 256;
  const int tile_n = (swz & 15) * 256;

  const __hip_bfloat16* At = A + (size_t)tile_m * K;  // SGPR base
  const __hip_bfloat16* Bt = B + (size_t)tile_n * K;

  // Staging invariants: chunk position p = c*512+tid; row=p>>3, slot=p&7
  // holds global chunk g = slot^(row&7)  (proven conflict-free swizzle).
  int soff[2], doff[2];
#pragma unroll
  for (int c = 0; c < 2; c++) {
    int p = c * 512 + tid;
    int row = p >> 3;
    int g = (p & 7) ^ (row & 7);
    soff[c] = row * K + g * 8;  // elems
    doff[c] = p * 8;            // elems into half-buffer
  }
  // Fragment read invariants (all local rows == fr mod 8 -> sel works).
  int aro[4], bro[2], co[2];
#pragma unroll
  for (int u = 0; u < 4; u++) aro[u] = (wr * 16 + u * 32 + fr) * 64;
#pragma unroll
  for (int j = 0; j < 2; j++) bro[j] = (wn * 16 + j * 64 + fr) * 64;
#pragma unroll
  for (int kk = 0; kk < 2; kk++) co[kk] = ((kk * 4 + quad) ^ sel) * 8;

  floatx4 acc[8][4];
#pragma unroll
  for (int i = 0; i < 8; i++)
#pragma unroll
    for (int j = 0; j < 4; j++) acc[i][j] = (floatx4){0.f, 0.f, 0.f, 0.f};

  bf16x8 af[4][2];     // A frags: [u][kk] for current m-half
  bf16x8 bf[2][2][2];  // B frags: [nh][jh][kk], both halves held

#define STAGE(GBASE, DST, TILE, HALF)                                    \
  do {                                                                   \
    const __hip_bfloat16* _s =                                           \
        GBASE + (size_t)(HALF) * 128 * K + (size_t)(TILE) * BK;          \
    _Pragma("unroll") for (int _c = 0; _c < 2; _c++) {                   \
      gload_lds16(_s + soff[_c], DST + doff[_c]);                        \
    }                                                                    \
  } while (0)

#define LOADA(SRC)                                                       \
  do {                                                                   \
    _Pragma("unroll") for (int _u = 0; _u < 4; _u++) {                   \
      _Pragma("unroll") for (int _kk = 0; _kk < 2; _kk++) {              \
        af[_u][_kk] = *(const bf16x8*)&SRC[aro[_u] + co[_kk]];           \
      }                                                                  \
    }                                                                    \
  } while (0)

#define LOADB(SRC, NH)                                                   \
  do {                                                                   \
    _Pragma("unroll") for (int _j = 0; _j < 2; _j++) {                   \
      _Pragma("unroll") for (int _kk = 0; _kk < 2; _kk++) {              \
        bf[NH][_j][_kk] = *(const bf16x8*)&SRC[bro[_j] + co[_kk]];       \
      }                                                                  \
    }                                                                    \
  } while (0)

#define MMA(MH, NH)                                                      \
  do {                                                                   \
    __builtin_amdgcn_s_setprio(1);                                       \
    _Pragma("unroll") for (int _kk = 0; _kk < 2; _kk++) {                \
      _Pragma("unroll") for (int _u = 0; _u < 4; _u++) {                 \
        _Pragma("unroll") for (int _j = 0; _j < 2; _j++) {               \
          acc[(MH) * 4 + _u][(NH) * 2 + _j] =                            \
              __builtin_amdgcn_mfma_f32_16x16x32_bf16(                   \
                  af[_u][_kk], bf[NH][_j][_kk],                          \
                  acc[(MH) * 4 + _u][(NH) * 2 + _j], 0, 0, 0);           \
        }                                                                \
      }                                                                  \
    }                                                                    \
    __builtin_amdgcn_s_setprio(0);                                       \
  } while (0)

#define BAR() __builtin_amdgcn_s_barrier()
#define WAITVM(N) asm volatile("s_waitcnt vmcnt(" #N ")" ::: "memory")
  // m201 phase sync: pin issue-segment above the barrier, drain LDS reads,
  // pin MFMA cluster below the wait.
#define PHASE_SYNC()                                                     \
  do {                                                                   \
    __builtin_amdgcn_sched_barrier(0);                                   \
    __builtin_amdgcn_s_barrier();                                        \
    asm volatile("s_waitcnt lgkmcnt(0)");                                \
    __builtin_amdgcn_sched_barrier(0);                                   \
  } while (0)

  // One K-tile, 4 phases, quadrants (0,0),(0,1),(1,1),(1,0).
  // AB0/AB1/BB0/BB1 = this tile's buffers; AN1/BN0 = next tile's (t+1)
  // stage targets; AB0/BB1 are restaged for t+2 at q3/q4 (after death).
#define TILE_BODY(T, AB0, AB1, BB0, BB1, AN1, BN0)                       \
  do {                                                                   \
    LOADA(AB0);                                                          \
    LOADB(BB0, 0);                                                       \
    STAGE(At, AN1, (T) + 1, 1);                                          \
    PHASE_SYNC();                                                        \
    MMA(0, 0);                                                           \
    BAR();                                                               \
    LOADB(BB1, 1);                                                       \
    STAGE(Bt, BN0, (T) + 1, 0);                                          \
    PHASE_SYNC();                                                        \
    MMA(0, 1);                                                           \
    BAR();                                                               \
    LOADA(AB1);                                                          \
    STAGE(At, AB0, (T) + 2, 0);                                          \
    PHASE_SYNC();                                                        \
    MMA(1, 1);                                                           \
    BAR();                                                               \
    STAGE(Bt, BB1, (T) + 2, 1);                                          \
    PHASE_SYNC();                                                        \
    MMA(1, 0);                                                           \
    WAITVM(4);                                                           \
    BAR();                                                               \
  } while (0)

  // ---- Prologue: tile0 fully + tile1 A-h0,B-h1.
  STAGE(At, As0h0, 0, 0);
  STAGE(Bt, Bs0h1, 0, 1);
  STAGE(At, As0h1, 0, 1);
  STAGE(Bt, Bs0h0, 0, 0);
  STAGE(At, As1h0, 1, 0);
  STAGE(Bt, Bs1h1, 1, 1);
  WAITVM(4);  // tile0's 8 loads complete; tile1's 4 in flight
  BAR();

  // ---- Main loop: tiles 0..61 as explicit (even, odd) pairs.
#pragma unroll 1
  for (int it = 0; it < (NT - 2) / 2; ++it) {
    const int t = it * 2;
    TILE_BODY(t, As0h0, As0h1, Bs0h0, Bs0h1, As1h1, Bs1h0);
    TILE_BODY(t + 1, As1h0, As1h1, Bs1h0, Bs1h1, As0h1, Bs0h0);
  }

  // ---- Tile 62 (buf0): stage only tile 63's A-h1/B-h0; drain at end.
  {
    LOADA(As0h0);
    LOADB(Bs0h0, 0);
    STAGE(At, As1h1, NT - 1, 1);
    PHASE_SYNC();
    MMA(0, 0);
    BAR();
    LOADB(Bs0h1, 1);
    STAGE(Bt, Bs1h0, NT - 1, 0);
    PHASE_SYNC();
    MMA(0, 1);
    BAR();
    LOADA(As0h1);
    PHASE_SYNC();
    MMA(1, 1);
    BAR();
    PHASE_SYNC();
    MMA(1, 0);
    WAITVM(0);  // tile 63 fully staged
    BAR();
  }
  // ---- Tile 63 (buf1): no stages, no waits.
  {
    LOADA(As1h0);
    LOADB(Bs1h0, 0);
    PHASE_SYNC();
    MMA(0, 0);
    BAR();
    LOADB(Bs1h1, 1);
    PHASE_SYNC();
    MMA(0, 1);
    BAR();
    LOADA(As1h1);
    PHASE_SYNC();
    MMA(1, 1);
    BAR();
    PHASE_SYNC();
    MMA(1, 0);
  }

#undef TILE_BODY
#undef PHASE_SYNC
#undef STAGE
#undef LOADA
#undef LOADB
#undef MMA
#undef BAR
#undef WAITVM

  // ---- Epilogue: C/D layout col = lane&15, row = quad*4 + reg.
#pragma unroll
  for (int i = 0; i < 8; i++) {
    int mb = tile_m + wr * 16 + i * 32 + quad * 4;
#pragma unroll
    for (int j = 0; j < 4; j++) {
      int n = tile_n + wn * 16 + j * 64 + fr;
#pragma unroll
      for (int r = 0; r < 4; r++) {
        C[(size_t)(mb + r) * N + n] = acc[i][j][r];
      }
    }
  }
}

// ---------------------------------------------------------------------------
extern "C" void kernel_launch(void* const* d_in, const int* in_sizes, int n_in,
                              void* d_out, int out_size, void* d_ws,
                              size_t ws_size, hipStream_t stream) {
  const float* inp = (const float*)d_in[0];     // [2,2048,4096] fp32
  const float* W = (const float*)d_in[1];       // [4096,4096] fp32
  const float* conv_w = (const float*)d_in[2];  // [4,1,3,3] fp32
  const float* conv_b = (const float*)d_in[3];  // [4] fp32
  const float* sk_wt = (const float*)d_in[4];   // [4,1,1] fp32
  float* out = (float*)d_out;                   // [2,2048,4096] fp32

  __hip_bfloat16* Wt = (__hip_bfloat16*)d_ws;   // 32 MB
  __hip_bfloat16* Ab =
      (__hip_bfloat16*)((char*)d_ws + (size_t)(32u << 20));  // next 32 MB

  // 1) merged prep: cast activations + transform weight, one launch
  prep<<<CAST_BLOCKS + TRANS_BLOCKS, 256, 0, stream>>>(inp, Ab, W, conv_w,
                                                       conv_b, sk_wt, Wt);
  // 2) out[m][n] = sum_k Ab[m][k] * Wt[n][k]  (256x256 tiles, 8-phase)
  dim3 grid(FOUT / 256, M_DIM / 256);
  gemm_nt<<<grid, 512, 0, stream>>>(Ab, Wt, out, M_DIM, FOUT, FIN);
}

// Round 3
// 287.499 us; speedup vs baseline: 1.0591x; 1.0591x over previous
//
#include <hip/hip_runtime.h>
#include <hip/hip_bf16.h>

#define FIN 4096
#define FOUT 4096
#define HEADS 4
#define ROWS_PER_HEAD (FOUT / HEADS)  // 1024
#define M_DIM 4096                    // 2*2048 flattened batch*seq

typedef __attribute__((ext_vector_type(8))) short bf16x8;   // 8 bf16 = 4 VGPRs
typedef __attribute__((ext_vector_type(4))) float floatx4;  // MFMA accum

#define CAST_BLOCKS ((M_DIM * FIN) / (256 * 8))      // 8192
#define TRANS_BLOCKS ((FOUT * FIN / 8) / 256)        // 8192

// ---------------------------------------------------------------------------
// Kernel 1 (merged prep, unchanged from R5-verified).
// ---------------------------------------------------------------------------
__global__ __launch_bounds__(256) void prep(
    const float* __restrict__ x,    // activations [M_DIM][FIN]
    __hip_bfloat16* __restrict__ y, // bf16 activations out
    const float* __restrict__ W,
    const float* __restrict__ cw,   // [HEADS][3][3]
    const float* __restrict__ cb,   // [HEADS]
    const float* __restrict__ sk,   // [HEADS]
    __hip_bfloat16* __restrict__ Wt) {
  if (blockIdx.x < CAST_BLOCKS) {
    int idx = blockIdx.x * 256 + threadIdx.x;  // one per 8 elements
    const float4* xv = (const float4*)x;
    float4 a = xv[idx * 2];
    float4 b = xv[idx * 2 + 1];
    __hip_bfloat16 t[8];
    t[0] = __float2bfloat16(a.x); t[1] = __float2bfloat16(a.y);
    t[2] = __float2bfloat16(a.z); t[3] = __float2bfloat16(a.w);
    t[4] = __float2bfloat16(b.x); t[5] = __float2bfloat16(b.y);
    t[6] = __float2bfloat16(b.z); t[7] = __float2bfloat16(b.w);
    *(bf16x8*)(&y[(size_t)idx * 8]) = *(bf16x8*)t;
    return;
  }

  int gid = (blockIdx.x - CAST_BLOCKS) * 256 + threadIdx.x;
  int o = gid >> 9;                          // output row (FIN/8 = 512)
  int fs = (gid & 511) << 3;                 // fin start, multiple of 8
  int h = o >> 10;                           // head
  int r = o & (ROWS_PER_HEAD - 1);

  float kk[3][3];
#pragma unroll
  for (int i = 0; i < 3; i++)
#pragma unroll
    for (int j = 0; j < 3; j++) kk[i][j] = cw[h * 9 + i * 3 + j];
  float sig = 1.0f / (1.0f + __expf(-sk[h]));

  float acc[8];
#pragma unroll
  for (int j = 0; j < 8; j++) acc[j] = cb[h];

#pragma unroll
  for (int dr = -1; dr <= 1; dr++) {
    int rr = r + dr;
    if (rr < 0 || rr >= ROWS_PER_HEAD) continue;
    const float* rp = W + ((size_t)(h * ROWS_PER_HEAD + rr)) * FIN + fs;
    float a[10];
    float4 v0 = *(const float4*)rp;
    float4 v1 = *(const float4*)(rp + 4);
    a[1] = v0.x; a[2] = v0.y; a[3] = v0.z; a[4] = v0.w;
    a[5] = v1.x; a[6] = v1.y; a[7] = v1.z; a[8] = v1.w;
    a[0] = (fs > 0) ? rp[-1] : 0.0f;
    a[9] = (fs + 8 < FIN) ? rp[8] : 0.0f;
#pragma unroll
    for (int j = 0; j < 8; j++)
      acc[j] += kk[dr + 1][0] * a[j] + kk[dr + 1][1] * a[j + 1] +
                kk[dr + 1][2] * a[j + 2];
    if (dr == 0) {
#pragma unroll
      for (int j = 0; j < 8; j++) acc[j] += sig * a[j + 1];
    }
  }
  __hip_bfloat16 t[8];
#pragma unroll
  for (int j = 0; j < 8; j++) t[j] = __float2bfloat16(acc[j]);
  *(bf16x8*)(&Wt[(size_t)o * FIN + fs]) = *(bf16x8*)t;
}

// ---------------------------------------------------------------------------
// Kernel 2: C[m][n] = sum_k A[m][k] * B[n][k]  (NT GEMM, bf16 in, FP32 out)
// R10: 256x256 tile, BK=64, 8 waves. Ring schedule: 8 clusters of 8 MFMA per
// K-tile at (m-half, k-half, n-half) granularity. Each cluster's fragments
// are ds_read 2-4 clusters AHEAD into register slots that are dead by then
// (zero extra VGPR vs R9: afr[2][4] + bfr[2][2][2] = 64 regs, same total).
// Counted lgkmcnt waits (segment-exact: 0/4/4/0 per tile) let LDS-read BW
// flow UNDER the MFMA pipe drain instead of serializing after it (the
// diagnosed R8/R9 failure: barrier-locked waves all stall at MFMA issue,
// then expose full LDS time behind lgkmcnt(0)). ONE barrier per tile (vs 8).
// vmcnt(0) sits >=2 clusters after its stage issue. Tile's last cluster (C8)
// is deferred past the barrier to hide the tile-top read bubble. Last tile
// peeled (no OOB staging). Issue order pinned by sched_barrier(0) +
// "memory"-clobbered waitcnt asm (rule #18).
// ---------------------------------------------------------------------------
__device__ static inline void gload_lds16(const void* g, void* l) {
  __builtin_amdgcn_global_load_lds(
      (const __attribute__((address_space(1))) void*)g,
      (__attribute__((address_space(3))) void*)l, 16, 0, 0);
}

#define BK 64
#define NT (FIN / BK)  // 64 K-tiles

__global__ __launch_bounds__(512, 2) void gemm_nt(
    const __hip_bfloat16* __restrict__ A,  // [M][K]
    const __hip_bfloat16* __restrict__ B,  // [N][K]  (= W_i, row-major)
    float* __restrict__ C,                 // [M][N] fp32
    int M, int N, int K) {
  // 8 distinct LDS objects (precise DMA alias info): 16 KB each, 128 KB.
  __shared__ __hip_bfloat16 As0h0[128 * BK];
  __shared__ __hip_bfloat16 As0h1[128 * BK];
  __shared__ __hip_bfloat16 As1h0[128 * BK];
  __shared__ __hip_bfloat16 As1h1[128 * BK];
  __shared__ __hip_bfloat16 Bs0h0[128 * BK];
  __shared__ __hip_bfloat16 Bs0h1[128 * BK];
  __shared__ __hip_bfloat16 Bs1h0[128 * BK];
  __shared__ __hip_bfloat16 Bs1h1[128 * BK];

  const int tid = threadIdx.x;
  const int lane = tid & 63;
  const int wave = tid >> 6;   // 0..7
  const int wr = wave >> 2;    // 0..1  (WARPS_M = 2)
  const int wn = wave & 3;     // 0..3  (WARPS_N = 4)
  const int fr = lane & 15;    // fragment row
  const int quad = lane >> 4;  // k-chunk selector
  const int sel = fr & 7;      // swizzle selector

  // XCD-chunked bijective swizzle (256 wgs % 8 == 0): 32 consecutive tiles
  // per XCD -> 2 A-panels (4 MB) L2-resident per XCD. Verified: FETCH-neutral
  // BW drop in R9 (1490->990 GB/s), schedule-bound so time-neutral; keep.
  const int orig = blockIdx.y * gridDim.x + blockIdx.x;
  const int swz = (orig & 7) * 32 + (orig >> 3);
  const int tile_m = (swz >> 4) * 256;
  const int tile_n = (swz & 15) * 256;

  const __hip_bfloat16* At = A + (size_t)tile_m * K;  // SGPR base
  const __hip_bfloat16* Bt = B + (size_t)tile_n * K;

  // Staging invariants: chunk position p = c*512+tid; row=p>>3, slot=p&7
  // holds global chunk g = slot^(row&7)  (proven conflict-free swizzle).
  int soff[2], doff[2];
#pragma unroll
  for (int c = 0; c < 2; c++) {
    int p = c * 512 + tid;
    int row = p >> 3;
    int g = (p & 7) ^ (row & 7);
    soff[c] = row * K + g * 8;  // elems
    doff[c] = p * 8;            // elems into half-buffer
  }
  // Fragment read invariants (all local rows == fr mod 8 -> sel works).
  int aro[4], bro[2], co[2];
#pragma unroll
  for (int u = 0; u < 4; u++) aro[u] = (wr * 16 + u * 32 + fr) * 64;
#pragma unroll
  for (int j = 0; j < 2; j++) bro[j] = (wn * 16 + j * 64 + fr) * 64;
#pragma unroll
  for (int kk = 0; kk < 2; kk++) co[kk] = ((kk * 4 + quad) ^ sel) * 8;

  floatx4 acc[8][4];
#pragma unroll
  for (int i = 0; i < 8; i++)
#pragma unroll
    for (int j = 0; j < 4; j++) acc[i][j] = (floatx4){0.f, 0.f, 0.f, 0.f};

  // Fragment ring: afr[mslot][u] (A m-half, current k-half);
  // bfr[kslot][nh][j] (B both n-halves, per k-half slot).
  bf16x8 afr[2][4];
  bf16x8 bfr[2][2][2];

#define STAGE(GBASE, DST, TILE, HALF)                                    \
  do {                                                                   \
    const __hip_bfloat16* _s =                                           \
        GBASE + (size_t)(HALF) * 128 * K + (size_t)(TILE) * BK;          \
    _Pragma("unroll") for (int _c = 0; _c < 2; _c++) {                   \
      gload_lds16(_s + soff[_c], DST + doff[_c]);                        \
    }                                                                    \
  } while (0)

#define LOADA4(MS, SRC, KK)                                              \
  do {                                                                   \
    _Pragma("unroll") for (int _u = 0; _u < 4; _u++) {                   \
      afr[MS][_u] = *(const bf16x8*)&SRC[aro[_u] + co[KK]];              \
    }                                                                    \
  } while (0)

#define LOADB2(KS, NH, SRC, KK)                                          \
  do {                                                                   \
    _Pragma("unroll") for (int _j = 0; _j < 2; _j++) {                   \
      bfr[KS][NH][_j] = *(const bf16x8*)&SRC[bro[_j] + co[KK]];          \
    }                                                                    \
  } while (0)

#define MMA8(MS, KS, NH)                                                 \
  do {                                                                   \
    __builtin_amdgcn_s_setprio(1);                                       \
    _Pragma("unroll") for (int _u = 0; _u < 4; _u++) {                   \
      _Pragma("unroll") for (int _j = 0; _j < 2; _j++) {                 \
        acc[(MS) * 4 + _u][(NH) * 2 + _j] =                              \
            __builtin_amdgcn_mfma_f32_16x16x32_bf16(                     \
                afr[MS][_u], bfr[KS][NH][_j],                            \
                acc[(MS) * 4 + _u][(NH) * 2 + _j], 0, 0, 0);             \
      }                                                                  \
    }                                                                    \
    __builtin_amdgcn_s_setprio(0);                                       \
  } while (0)

#define BAR() __builtin_amdgcn_s_barrier()
#define WAITVM(N) asm volatile("s_waitcnt vmcnt(" #N ")" ::: "memory")
#define FENCE_LGKM(N)                                                    \
  do {                                                                   \
    __builtin_amdgcn_sched_barrier(0);                                   \
    asm volatile("s_waitcnt lgkmcnt(" #N ")" ::: "memory");              \
    __builtin_amdgcn_sched_barrier(0);                                   \
  } while (0)

  // One K-tile. Clusters C1..C7 here; C8 = MMA8(1,1,0) deferred past the
  // barrier (runs at the top of the NEXT tile body, hiding the read bubble).
  // Read segments: S_A(8: af m0k0 + bf k0) | S_B(4: af m1k0) |
  // S_C(4: bf k1) | S_D(4: af m0k1) | S_E(4: af m1k1).
  // Waits: C1 needs S_A -> lgkm(0); C3 needs S_B (S_C after it) -> lgkm(4);
  // C5 needs S_C+S_D (S_E after) -> lgkm(4); C7 needs S_E -> lgkm(0).
  // Slot liveness (audited): afr[0]: m0k0 dies@C2 < S_D write; afr[1]: m1k0
  // dies@C4 < S_E write; bfr[1]: prev-k1 dies@C8(top) < S_C write; bfr[0]:
  // prev-k0 dies@C4(prev tile) < S_A write. Stages -> nbuf (last read 2
  // barriers ago); vmcnt(0) covers all 8 before BAR.
#define TBODY(T, CA0, CA1, CB0, CB1, NA0, NA1, NB0, NB1, DO_C8, DO_STAGE) \
  do {                                                                    \
    LOADA4(0, CA0, 0);                                                    \
    LOADB2(0, 0, CB0, 0);                                                 \
    LOADB2(0, 1, CB1, 0);                                                 \
    if (DO_C8) MMA8(1, 1, 0); /* prev tile's C8 */                        \
    FENCE_LGKM(0);                                                        \
    MMA8(0, 0, 0); /* C1 */                                               \
    LOADA4(1, CA1, 0); /* S_B */                                          \
    MMA8(0, 0, 1); /* C2 */                                               \
    LOADB2(1, 0, CB0, 1); /* S_C */                                       \
    LOADB2(1, 1, CB1, 1);                                                 \
    if (DO_STAGE) {                                                       \
      STAGE(At, NA0, (T) + 1, 0);                                         \
      STAGE(At, NA1, (T) + 1, 1);                                         \
    }                                                                     \
    FENCE_LGKM(4);                                                        \
    MMA8(1, 0, 1); /* C3 */                                               \
    LOADA4(0, CA0, 1); /* S_D */                                          \
    MMA8(1, 0, 0); /* C4 */                                               \
    LOADA4(1, CA1, 1); /* S_E */                                          \
    FENCE_LGKM(4);                                                        \
    MMA8(0, 1, 0); /* C5 */                                               \
    if (DO_STAGE) {                                                       \
      STAGE(Bt, NB0, (T) + 1, 0);                                         \
      STAGE(Bt, NB1, (T) + 1, 1);                                         \
    }                                                                     \
    MMA8(0, 1, 1); /* C6 */                                               \
    FENCE_LGKM(0);                                                        \
    MMA8(1, 1, 1); /* C7 */                                               \
    if (DO_STAGE) WAITVM(0);                                              \
    BAR();                                                                \
  } while (0)

  // ---- Prologue: stage tile0 fully into buf0.
  STAGE(At, As0h0, 0, 0);
  STAGE(At, As0h1, 0, 1);
  STAGE(Bt, Bs0h0, 0, 0);
  STAGE(Bt, Bs0h1, 0, 1);
  WAITVM(0);
  BAR();

  // ---- Tile 0 (buf0, no deferred C8 yet).
  TBODY(0, As0h0, As0h1, Bs0h0, Bs0h1, As1h0, As1h1, Bs1h0, Bs1h1, 0, 1);

  // ---- Tiles 1..62 as explicit (odd, even) pairs; compile-time buffers.
#pragma unroll 1
  for (int t = 1; t < NT - 1; t += 2) {
    TBODY(t, As1h0, As1h1, Bs1h0, Bs1h1, As0h0, As0h1, Bs0h0, Bs0h1, 1, 1);
    TBODY(t + 1, As0h0, As0h1, Bs0h0, Bs0h1, As1h0, As1h1, Bs1h0, Bs1h1, 1, 1);
  }

  // ---- Tile 63 (buf1): no staging, then the final deferred C8.
  TBODY(NT - 1, As1h0, As1h1, Bs1h0, Bs1h1, As0h0, As0h1, Bs0h0, Bs0h1, 1, 0);
  MMA8(1, 1, 0);  // tile 63's C8

#undef TBODY
#undef FENCE_LGKM
#undef STAGE
#undef LOADA4
#undef LOADB2
#undef MMA8
#undef BAR
#undef WAITVM

  // ---- Epilogue: C/D layout col = lane&15, row = quad*4 + reg.
#pragma unroll
  for (int i = 0; i < 8; i++) {
    int mb = tile_m + wr * 16 + i * 32 + quad * 4;
#pragma unroll
    for (int j = 0; j < 4; j++) {
      int n = tile_n + wn * 16 + j * 64 + fr;
#pragma unroll
      for (int r = 0; r < 4; r++) {
        C[(size_t)(mb + r) * N + n] = acc[i][j][r];
      }
    }
  }
}

// ---------------------------------------------------------------------------
extern "C" void kernel_launch(void* const* d_in, const int* in_sizes, int n_in,
                              void* d_out, int out_size, void* d_ws,
                              size_t ws_size, hipStream_t stream) {
  const float* inp = (const float*)d_in[0];     // [2,2048,4096] fp32
  const float* W = (const float*)d_in[1];       // [4096,4096] fp32
  const float* conv_w = (const float*)d_in[2];  // [4,1,3,3] fp32
  const float* conv_b = (const float*)d_in[3];  // [4] fp32
  const float* sk_wt = (const float*)d_in[4];   // [4,1,1] fp32
  float* out = (float*)d_out;                   // [2,2048,4096] fp32

  __hip_bfloat16* Wt = (__hip_bfloat16*)d_ws;   // 32 MB
  __hip_bfloat16* Ab =
      (__hip_bfloat16*)((char*)d_ws + (size_t)(32u << 20));  // next 32 MB

  // 1) merged prep: cast activations + transform weight, one launch
  prep<<<CAST_BLOCKS + TRANS_BLOCKS, 256, 0, stream>>>(inp, Ab, W, conv_w,
                                                       conv_b, sk_wt, Wt);
  // 2) out[m][n] = sum_k Ab[m][k] * Wt[n][k]  (256x256 tiles, ring schedule)
  dim3 grid(FOUT / 256, M_DIM / 256);
  gemm_nt<<<grid, 512, 0, stream>>>(Ab, Wt, out, M_DIM, FOUT, FIN);
}